// Round 3
// baseline (430.980 us; speedup 1.0000x reference)
//
#include <hip/hip_runtime.h>
#include <hip/hip_bf16.h>

// ModulationConvBlock: per-sample modulated/demodulated 3x3 conv.
// fp32 in/out, bf16 MFMA internally. B=8, IN_C=OUT_C=256, H=W=128, K=3.
//
// Round-8: occupancy attack on k_conv — 512-thread blocks (8 waves) on the same
// 128oc x 128px tile; LDS unchanged (64.25 KB) -> 2 blocks/CU -> 4 waves/SIMD
// (was 2). Per-wave: acc[4][2], 24 MFMA/stage, 1 X + 3 W global loads.
// Keeps: 1-barrier/stage pipeline, write-late DSW, XOR swizzle, setprio, T1 swizzle.
//
// ws layout: Wt 9.00 MiB | norm2 8 KiB | Xt bc*8 MiB

typedef __attribute__((ext_vector_type(8))) short short8;
typedef __attribute__((ext_vector_type(4))) float floatx4;
typedef __attribute__((ext_vector_type(4))) unsigned short ushort4_t;
typedef __bf16 bf16x8 __attribute__((ext_vector_type(8)));

#define B_    8
#define IC_   256
#define OC_   256
#define HW_   128
#define PIX_  (HW_*HW_)
#define RTOT  2304                  // 9*256, k-order: tap-major, ic-minor
#define WSCALE (1.0f/48.0f)         // 1/sqrt(3*3*256)

// XOR swizzle: 16B slot within a 64B row, keyed on row bits 0..3.
#define SWZ(row) ((((row) ^ ((row) >> 2)) & 3) << 3)

static __device__ __forceinline__ floatx4 mfma_bf16(short8 a, short8 b, floatx4 c) {
  return __builtin_amdgcn_mfma_f32_16x16x32_bf16(
      __builtin_bit_cast(bf16x8, a), __builtin_bit_cast(bf16x8, b), c, 0, 0, 0);
}

static __device__ __forceinline__ unsigned short f2bf(float f) {
  unsigned int u = __builtin_bit_cast(unsigned int, f);
  return (unsigned short)(u >> 16) + (unsigned short)((u >> 15) & 1u);
}

// ---------------- Z: zero norm2 ----------------
__global__ __launch_bounds__(256) void k_zero(float* __restrict__ p, int n) {
  int i = blockIdx.x * 256 + threadIdx.x;
  if (i < n) p[i] = 0.f;
}

// ---------------- K0: NCHW fp32 -> NHWC bf16 transpose (chunk of bc batches) ------
__global__ __launch_bounds__(256) void k_transpose(const float* __restrict__ x,
                                                   unsigned short* __restrict__ Xt,
                                                   int b0) {
  __shared__ unsigned short t[64][66];                    // [ic_local][px_local], pad 66
  const int tid = threadIdx.x;
  const int p0 = blockIdx.x * 64, ic0 = blockIdx.y * 64, bz = blockIdx.z;
  const float* xb = x + (size_t)(b0 + bz) * IC_ * PIX_;
  unsigned short* xtb = Xt + (size_t)bz * PIX_ * IC_;     // chunk-local

  const int c2 = tid & 15, r2 = tid >> 4;                 // c2: px/4 group, r2: ic row base
#pragma unroll
  for (int jr = 0; jr < 4; ++jr) {
    const int row = r2 + jr * 16;                         // ic_local
    floatx4 f = *(const floatx4*)(&xb[(size_t)(ic0 + row) * PIX_ + p0 + 4 * c2]);
    ushort4_t w = { f2bf(f[0]), f2bf(f[1]), f2bf(f[2]), f2bf(f[3]) };
    *(ushort4_t*)(&t[row][4 * c2]) = w;                   // single b64 LDS write
  }
  __syncthreads();
#pragma unroll
  for (int jj = 0; jj < 4; ++jj) {
    const int px = r2 + jj * 16;
    ushort4_t v = { t[4 * c2 + 0][px], t[4 * c2 + 1][px],
                    t[4 * c2 + 2][px], t[4 * c2 + 3][px] };
    *(ushort4_t*)(&xtb[(size_t)(p0 + px) * IC_ + ic0 + 4 * c2]) = v;   // 8B store
  }
}

// ---------------- A1: demod norms (fp32) ----------------
__global__ __launch_bounds__(256) void k_norm(const float* __restrict__ Wraw,
                                              const float* __restrict__ code,
                                              float* __restrict__ norm2) {
  const int tap = blockIdx.x % 9, b = blockIdx.x / 9;
  const int oc = threadIdx.x;
  __shared__ float cs[IC_];
  cs[oc] = code[b * IC_ + oc];
  __syncthreads();
  float s = 0.f;
#pragma unroll 8
  for (int ic = 0; ic < IC_; ++ic) {
    float v = Wraw[(size_t)(tap * IC_ + ic) * OC_ + oc] * cs[ic];
    s += v * v;
  }
  atomicAdd(&norm2[b * OC_ + oc], s * (WSCALE * WSCALE));
}

// ---------------- A2: write modulated+demodulated weights (bf16) ----------------
__global__ __launch_bounds__(256) void k_modw(const float* __restrict__ Wraw,
                                              const float* __restrict__ code,
                                              const float* __restrict__ norm2,
                                              unsigned short* __restrict__ Wt) {
  const int idx = blockIdx.x * 256 + threadIdx.x;   // idx = ((b*256 + oc)*2304 + r)
  const int r  = idx % RTOT;
  const int t2 = idx / RTOT;
  const int oc = t2 & 255;
  const int b  = t2 >> 8;
  const int ic = r & 255;
  const float w  = Wraw[(size_t)r * OC_ + oc];
  const float cd = code[b * IC_ + ic];
  const float rn = rsqrtf(norm2[b * OC_ + oc] + 1e-8f);
  Wt[idx] = f2bf(w * cd * WSCALE * rn);
}

// ---------------- K3: implicit-GEMM conv, pipelined, 8 waves/block ---------------
// Block = 128oc x 128px (one image row), 512 threads. Stage s = (iy, icc).
// Wave w: wm=w&1 (64-oc half), wn=w>>1 (32-px quarter). acc[4][2].
// Pipeline: CLOAD(s+1) -> 24 MFMA/wave (setprio) on buf(s&1) -> DSW buf(s&1^1) -> barrier.
__global__ __launch_bounds__(512, 4) void k_conv(const unsigned short* __restrict__ Xt,
                                                 const unsigned short* __restrict__ Wt,
                                                 const float* __restrict__ bias,
                                                 float* __restrict__ out,
                                                 int b0) {
  __shared__ __align__(16) unsigned short Wl[2][3][128 * 32];   // 48 KiB
  __shared__ __align__(16) unsigned short Xl[2][130 * 32];      // 16.25 KiB

  const int tid  = threadIdx.x;
  const int lane = tid & 63;
  const int wv   = tid >> 6;          // wave id 0..7
  const int wm   = wv & 1;            // oc-half (64)
  const int wn   = wv >> 1;           // px-quarter (32), 0..3
  const int l15  = lane & 15;
  const int k0   = (lane >> 4) * 8;   // frag k-offset (elements)

  // T1: bijective XCD-chunk block swizzle (nwg = 256*bc, always %8==0)
  const int nwg  = (int)(gridDim.x * gridDim.y * gridDim.z);
  const int q    = nwg >> 3;
  const int flat = (int)(blockIdx.x + gridDim.x * (blockIdx.y + gridDim.y * blockIdx.z));
  const int nf   = (flat & 7) * q + (flat >> 3);
  const int py = nf & 127, ot = (nf >> 7) & 1, bz = nf >> 8;
  const int b  = b0 + bz;

  const unsigned short* Wtp = Wt + (size_t)(b * OC_ + ot * 128) * RTOT;
  const unsigned short* Xtp = Xt + (size_t)bz * PIX_ * IC_;   // chunk-local

  // staging thread mapping: 4 threads per row, one 16B quarter each
  const int srow = tid >> 2;          // 0..127 (X row = srow+1; W row = srow)
  const int sq   = tid & 3;           // 16B quarter
  const int sOffW = (sq * 8) ^ SWZ(srow);      // swizzled elem offset in 32-elem row
  const int sOffX = (sq * 8) ^ SWZ(srow + 1);

  // read-side swizzles
  const int sA  = SWZ(l15);
  const int sB0 = SWZ(l15 + 0), sB1 = SWZ(l15 + 1), sB2 = SWZ(l15 + 2);

  const int lo = (py > 0) ? py - 1 : 0;
  const int hi = (py < HW_ - 1) ? py + 1 : HW_ - 1;
  const int NS = (hi - lo + 1) * 8;   // 16 or 24, block-uniform

  const floatx4 zz = {0.f, 0.f, 0.f, 0.f};
  floatx4 acc[4][2];
#pragma unroll
  for (int i = 0; i < 4; ++i)
#pragma unroll
    for (int j = 0; j < 2; ++j) acc[i][j] = zz;

  // zero padding rows (px=-1 -> row 0, px=128 -> row 129) of BOTH buffers
  if (tid < 128) {
    const int bi = tid >> 6, rr = tid & 63;
    const int r = (rr < 32) ? 0 : 129;
    Xl[bi][r * 32 + (rr & 31)] = 0;
  }

  short8 xr0, wr0, wr1, wr2;

#define CLOAD(s_) do {                                                           \
    const int iy_   = lo + ((s_) >> 3);                                          \
    const int icc_  = (s_) & 7;                                                  \
    const int tapb_ = (iy_ - py + 1) * 3;                                        \
    const unsigned short* xs_ =                                                  \
        Xtp + (size_t)(iy_ * HW_ + srow) * IC_ + icc_ * 32 + sq * 8;             \
    xr0 = *(const short8*)(xs_);                                                 \
    const unsigned short* ws_ =                                                  \
        Wtp + (size_t)srow * RTOT + (size_t)tapb_ * IC_ + icc_ * 32 + sq * 8;    \
    wr0 = *(const short8*)(ws_);                                                 \
    wr1 = *(const short8*)(ws_ + IC_);                                           \
    wr2 = *(const short8*)(ws_ + 2 * IC_);                                       \
  } while (0)

#define DSW(b_) do {                                                             \
    *(short8*)(&Xl[b_][(srow + 1) * 32 + sOffX])  = xr0;                         \
    *(short8*)(&Wl[b_][0][srow * 32 + sOffW])     = wr0;                         \
    *(short8*)(&Wl[b_][1][srow * 32 + sOffW])     = wr1;                         \
    *(short8*)(&Wl[b_][2][srow * 32 + sOffW])     = wr2;                         \
  } while (0)

  // prologue: stage 0 into buf 0
  CLOAD(0);
  DSW(0);
  __syncthreads();

  for (int s = 0; s < NS; ++s) {
    const int nb = s & 1;
    if (s + 1 < NS) CLOAD(s + 1);     // issue next-stage global loads

    __builtin_amdgcn_s_setprio(1);
#pragma unroll
    for (int kx = 0; kx < 3; ++kx) {
      const int sB = (kx == 0) ? sB0 : (kx == 1) ? sB1 : sB2;
      short8 af[4], bfr[2];
#pragma unroll
      for (int i = 0; i < 4; ++i)
        af[i] = *(const short8*)(&Wl[nb][kx][(wm * 64 + i * 16 + l15) * 32 + (k0 ^ sA)]);
#pragma unroll
      for (int j = 0; j < 2; ++j)
        bfr[j] = *(const short8*)(&Xl[nb][(wn * 32 + j * 16 + l15 + kx) * 32 + (k0 ^ sB)]);
#pragma unroll
      for (int i = 0; i < 4; ++i)
#pragma unroll
        for (int j = 0; j < 2; ++j)
          acc[i][j] = mfma_bf16(af[i], bfr[j], acc[i][j]);
    }
    __builtin_amdgcn_s_setprio(0);

    if (s + 1 < NS) DSW(nb ^ 1);      // write-late into the other buffer
    __syncthreads();                  // ONE barrier per stage
  }

#undef CLOAD
#undef DSW

  // epilogue: bias + LeakyReLU(0.2)*sqrt(2); C/D: col=lane&15 (px), row=(lane>>4)*4+p (oc)
  const int row0 = (lane >> 4) * 4;
#pragma unroll
  for (int i = 0; i < 4; ++i) {
#pragma unroll
    for (int p = 0; p < 4; ++p) {
      const int oc = ot * 128 + wm * 64 + i * 16 + row0 + p;
      const float bvf = bias[oc];
#pragma unroll
      for (int j = 0; j < 2; ++j) {
        const int px = wn * 32 + j * 16 + l15;
        float v = acc[i][j][p] + bvf;
        v = (v >= 0.f ? v : 0.2f * v) * 1.41421356237f;
        out[((size_t)(b * OC_ + oc) * HW_ + py) * HW_ + px] = v;   // fp32 store
      }
    }
  }
}

extern "C" void kernel_launch(void* const* d_in, const int* in_sizes, int n_in,
                              void* d_out, int out_size, void* d_ws, size_t ws_size,
                              hipStream_t stream) {
  const float* x    = (const float*)d_in[0];   // fp32 [8,256,128,128]
  const float* code = (const float*)d_in[1];   // fp32 [8,256]
  const float* wgt  = (const float*)d_in[2];   // fp32 [256,256,3,3] flat
  const float* bias = (const float*)d_in[3];   // fp32 [256]

  const size_t WT_BYTES = (size_t)B_ * OC_ * RTOT * 2;   // 9,437,184
  const size_t N2_BYTES = (size_t)B_ * OC_ * 4;          // 8,192
  const size_t XT_OFF   = WT_BYTES + N2_BYTES;           // 256B-aligned
  const size_t XB_BYTES = (size_t)PIX_ * IC_ * 2;        // 8 MiB per batch image

  unsigned short* Wt = (unsigned short*)d_ws;
  float* norm2       = (float*)((char*)d_ws + WT_BYTES);
  unsigned short* Xt = (unsigned short*)((char*)d_ws + XT_OFF);

  // Largest batch-chunk that fits ws_size (deterministic per ws_size -> graph-safe).
  int bc = 8;
  while (bc > 1 && XT_OFF + (size_t)bc * XB_BYTES > ws_size) bc >>= 1;

  k_zero<<<(B_ * OC_ + 255) / 256, 256, 0, stream>>>(norm2, B_ * OC_);
  k_norm<<<B_ * 9, 256, 0, stream>>>(wgt, code, norm2);
  k_modw<<<(B_ * OC_ * RTOT) / 256, 256, 0, stream>>>(wgt, code, norm2, Wt);
  for (int b0 = 0; b0 < B_; b0 += bc) {
    k_transpose<<<dim3(PIX_ / 64, IC_ / 64, bc), 256, 0, stream>>>(x, Xt, b0);
    k_conv<<<dim3(HW_, 2, bc), 512, 0, stream>>>(Xt, Wt, bias, (float*)d_out, b0);
  }
}